// Round 12
// baseline (59.621 us; speedup 1.0000x reference)
//
#include <hip/hip_runtime.h>

// NT-Xent loss, fused + TRIANGULAR: S = zn8 zn8^T is symmetric exactly
// (FP products commute, same k-order), and rowsum_i exp = colsum_i exp.
// Compute only 16-col tiles ct16 >= rt16; each above-diag tile contributes
// its exps to (a) row-sums of its rows, (b) via in-tile column reduction,
// row-sums of its transpose rows. Diagonal tiles: row-sums only, masked.
// Positive pair S[i][i+4096] lives in upper tri -> write pos[i], pos[i+4096].
// nll_r = -pos_r + 2 + log(total_r); out = mean(nll).
//
// Work = 8320 equal units (rb in 0..63, ph in [4rb,256)), flat-listed;
// grid 1040 blocks x 8 units. Deterministic fixed-slot partials:
// rsum[row][36] (row-direct, slot per block-segment), tsum[col][64]
// (transpose, slot = contributing rb), zeroed first. Inner machinery
// (fp8, LDS stage/swizzle, fragments) = R11 verified code.

#define NHALF 4096
#define N2 8192
#define D 256
#define RSLOT 36
#define TSLOT 64
#define NBLK 1040
#define UPB 8

typedef __attribute__((ext_vector_type(4))) float f32x4;

__device__ __forceinline__ unsigned char f2fp8(float f) {
  // OCP e4m3fn, RNE; inputs |f| <= 1 (normalized rows): no sat/NaN path.
  unsigned int u = __float_as_uint(f);
  unsigned char s = (unsigned char)((u >> 24) & 0x80u);
  int e = (int)((u >> 23) & 0xffu) - 127;
  unsigned int m = u & 0x7fffffu;
  if (e >= -6) {
    unsigned int r = m + 0x7ffffu + ((m >> 20) & 1u);
    if (r >= 0x800000u) { r = 0; ++e; } else r >>= 20;
    return (unsigned char)(s | (unsigned int)((e + 7) << 3) | r);
  }
  int q = (int)rintf(fabsf(f) * 512.0f);
  return (unsigned char)(s | (unsigned int)q);
}

__device__ __forceinline__ void gload_lds16(const void* g, void* l) {
  __builtin_amdgcn_global_load_lds(
      (const __attribute__((address_space(1))) unsigned int*)g,
      (__attribute__((address_space(3))) unsigned int*)l, 16, 0, 0);
}

__device__ __forceinline__ int cum_units(int rb) { return 258 * rb - 2 * rb * rb; }

// ---------------- Kernel 0: zero the partial-sum arrays ----------------
__global__ __launch_bounds__(256) void zero_kernel(float4* __restrict__ p) {
  p[blockIdx.x * 256 + threadIdx.x] = (float4){0.f, 0.f, 0.f, 0.f};
}

// ---------------- Kernel 1: row-normalize to fp8 ----------------
__global__ __launch_bounds__(256) void norm_kernel(const float* __restrict__ z1,
                                                   const float* __restrict__ z2,
                                                   unsigned char* __restrict__ zn8) {
  const int lane = threadIdx.x & 63;
  const int row = blockIdx.x * 4 + (threadIdx.x >> 6);
  const float* src = (row < NHALF) ? (z1 + (size_t)row * D)
                                   : (z2 + (size_t)(row - NHALF) * D);
  const float4 v = *(const float4*)(src + lane * 4);
  float ss = v.x * v.x + v.y * v.y + v.z * v.z + v.w * v.w;
  #pragma unroll
  for (int m = 1; m < 64; m <<= 1) ss += __shfl_xor(ss, m);
  const float inv = 1.0f / fmaxf(sqrtf(ss), 1e-8f);
  unsigned int o = (unsigned int)f2fp8(v.x * inv) |
                   ((unsigned int)f2fp8(v.y * inv) << 8) |
                   ((unsigned int)f2fp8(v.z * inv) << 16) |
                   ((unsigned int)f2fp8(v.w * inv) << 24);
  *(unsigned int*)(zn8 + (size_t)row * D + lane * 4) = o;
}

// ---------------- Kernel 2: triangular fused Gram + exp-sums ----------------
__global__ __launch_bounds__(256, 4) void simtri_kernel(const unsigned char* __restrict__ zn8,
                                                        float* __restrict__ tsum,
                                                        float* __restrict__ rsum,
                                                        float* __restrict__ pos_ws) {
  __shared__ __align__(16) char bsm[16384];       // 2 x 8 KB B tiles
  __shared__ float colred[2][4][32];              // dbuf col-partials
  const int lane = threadIdx.x & 63;
  const int wave = threadIdx.x >> 6;
  const int r16 = lane & 15;
  const int h = lane >> 4;  // 0..3

  // Decode first unit (rb, ph) of this block; exact at boundaries
  // (disc is a perfect square there), integer fixup for safety.
  const int idx0 = blockIdx.x * UPB;
  int rb = (int)((258.0f - sqrtf(66564.0f - 8.0f * (float)idx0)) * 0.25f);
  if (rb < 0) rb = 0;
  if (rb > 63) rb = 63;
  while (rb < 63 && cum_units(rb + 1) <= idx0) ++rb;
  while (rb > 0 && cum_units(rb) > idx0) --rb;
  int ph = 4 * rb + (idx0 - cum_units(rb));

  // Stage 2 tiles (8 KB) of cols [ph*32, +32) into LDS buffer `bf`.
  // Same layout/swizzle as R11: inner ^= (col&3)<<5 on source AND read.
  auto stage = [&](int bf, int p) {
    const int colbase = p * 32;
    #pragma unroll
    for (int s = 0; s < 2; ++s) {
      const int y = s * 4096 + wave * 1024 + lane * 16;
      const int col = (y >> 8) & 15;
      const int inner = (y & 255) ^ ((col & 3) << 5);
      const void* gp = zn8 + (size_t)(colbase + (y >> 12) * 16 + col) * D + inner;
      void* lp = bsm + bf * 8192 + s * 4096 + wave * 1024;  // +lane*16 by HW
      gload_lds16(gp, lp);
    }
  };

  long a[2][8];
  float lsum[2][4];
  int cur_rb = -1, slot = 0;
  int buf = 0, cbuf = 0, prev_ph = 0, prev_rb = 0;

  stage(0, ph);
  __syncthreads();

  for (int u = 0; u < UPB; ++u) {
    int rbn = rb, phn = ph + 1;
    if (phn == 256) { ++rbn; phn = 4 * rbn; }

    if (rb != cur_rb) {
      if (cur_rb >= 0) {
        // flush row-sums of finished segment
        #pragma unroll
        for (int st = 0; st < 2; ++st)
          #pragma unroll
          for (int g = 0; g < 4; ++g) {
            #pragma unroll
            for (int m = 1; m < 16; m <<= 1)
              lsum[st][g] += __shfl_xor(lsum[st][g], m);
          }
        if (r16 == 0) {
          #pragma unroll
          for (int st = 0; st < 2; ++st)
            #pragma unroll
            for (int g = 0; g < 4; ++g) {
              const int row = cur_rb * 128 + wave * 32 + st * 16 + (h << 2) + g;
              rsum[(size_t)row * RSLOT + slot] = lsum[st][g];
            }
        }
      }
      // load A for new rb (2 stripes x 8 steps, 8B/lane = 32 VGPR)
      #pragma unroll
      for (int st = 0; st < 2; ++st) {
        const unsigned char* ap =
            zn8 + (size_t)(rb * 128 + wave * 32 + st * 16 + r16) * D + h * 8;
        #pragma unroll
        for (int s = 0; s < 8; ++s) a[st][s] = *(const long*)(ap + s * 32);
      }
      #pragma unroll
      for (int st = 0; st < 2; ++st)
        #pragma unroll
        for (int s = 0; s < 8; ++s) asm volatile("" : "+v"(a[st][s]));
      #pragma unroll
      for (int st = 0; st < 2; ++st)
        #pragma unroll
        for (int g = 0; g < 4; ++g) lsum[st][g] = 0.0f;
      cur_rb = rb;
      slot = ((ph - 4 * rb) + 7) >> 3;  // distinct per segment (see R12 notes)
    }

    if (u + 1 < UPB) stage(buf ^ 1, phn);  // DMA overlaps compute

    // reduce previous unit's col-partials -> tsum (during this unit's MFMAs)
    if (u > 0 && h == 0 && r16 < 8) {
      const int c32 = wave * 8 + r16;
      const int pb = cbuf ^ 1;
      const float sm = colred[pb][0][c32] + colred[pb][1][c32] +
                       colred[pb][2][c32] + colred[pb][3][c32];
      tsum[(size_t)(prev_ph * 32 + c32) * TSLOT + prev_rb] = sm;
    }

    const char* base = bsm + buf * 8192;
    #pragma unroll
    for (int j = 0; j < 2; ++j) {
      const int ct16 = ph * 2 + j;
      const char* tb = base + j * 4096 + r16 * 256;
      const int sw = (r16 & 3) << 5;
      f32x4 acc0 = (f32x4){0.f, 0.f, 0.f, 0.f};
      f32x4 acc1 = (f32x4){0.f, 0.f, 0.f, 0.f};
      #pragma unroll
      for (int s = 0; s < 8; ++s) {
        const long b = *(const long*)(tb + ((s * 32 + h * 8) ^ sw));
        acc0 = __builtin_amdgcn_mfma_f32_16x16x32_fp8_fp8(a[0][s], b, acc0, 0, 0, 0);
        acc1 = __builtin_amdgcn_mfma_f32_16x16x32_fp8_fp8(a[1][s], b, acc1, 0, 0, 0);
      }
      float cpart = 0.0f;
      #pragma unroll
      for (int st = 0; st < 2; ++st) {
        const f32x4& acc = st ? acc1 : acc0;
        const int rt = rb * 8 + wave * 2 + st;
        if (ct16 >= rt) {               // below-diag stripes skipped
          const bool isd = (ct16 == rt);
          const bool isp = (ct16 == rt + 256);
          float cps = 0.0f;
          #pragma unroll
          for (int g = 0; g < 4; ++g) {
            const int rl = (h << 2) + g;
            float e = __expf(fmaf(acc[g], 2.0f, -2.0f));
            if (isd && r16 == rl) e = 0.0f;  // mask self-similarity
            if (isp && r16 == rl) {
              const int row = rb * 128 + wave * 32 + st * 16 + rl;
              const float s2 = acc[g] * 2.0f;
              pos_ws[row] = s2;
              pos_ws[row + NHALF] = s2;      // symmetric positive
            }
            lsum[st][g] += e;
            cps += e;
          }
          if (!isd) cpart += cps;            // diag tiles: no transpose term
        }
      }
      // column-sum over the wave's 32 rows (xor across the 4 h-groups)
      cpart += __shfl_xor(cpart, 16);
      cpart += __shfl_xor(cpart, 32);
      if (h == 0) colred[cbuf][wave][j * 16 + r16] = cpart;
    }

    prev_ph = ph;
    prev_rb = rb;
    __syncthreads();  // drains DMA + LDS before buffer swap
    buf ^= 1;
    cbuf ^= 1;
    rb = rbn;
    ph = phn;
  }

  // drain: reduce last unit's col-partials
  if (h == 0 && r16 < 8) {
    const int c32 = wave * 8 + r16;
    const int pb = cbuf ^ 1;
    const float sm = colred[pb][0][c32] + colred[pb][1][c32] +
                     colred[pb][2][c32] + colred[pb][3][c32];
    tsum[(size_t)(prev_ph * 32 + c32) * TSLOT + prev_rb] = sm;
  }
  // drain: flush final row-sum segment
  #pragma unroll
  for (int st = 0; st < 2; ++st)
    #pragma unroll
    for (int g = 0; g < 4; ++g) {
      #pragma unroll
      for (int m = 1; m < 16; m <<= 1)
        lsum[st][g] += __shfl_xor(lsum[st][g], m);
    }
  if (r16 == 0) {
    #pragma unroll
    for (int st = 0; st < 2; ++st)
      #pragma unroll
      for (int g = 0; g < 4; ++g) {
        const int row = cur_rb * 128 + wave * 32 + st * 16 + (h << 2) + g;
        rsum[(size_t)row * RSLOT + slot] = lsum[st][g];
      }
  }
}

// ---------------- Kernel 3a: per-row nll + per-block partial sum ----------------
__global__ __launch_bounds__(256) void nll_kernel(const float* __restrict__ tsum,
                                                  const float* __restrict__ rsum,
                                                  const float* __restrict__ pos_ws,
                                                  float* __restrict__ partial) {
  const int r = blockIdx.x * 256 + threadIdx.x;
  float t = 0.0f;
  const float4* tp = (const float4*)(tsum + (size_t)r * TSLOT);
  #pragma unroll
  for (int i = 0; i < TSLOT / 4; ++i) {
    const float4 v = tp[i];
    t += v.x + v.y + v.z + v.w;
  }
  const float4* rp = (const float4*)(rsum + (size_t)r * RSLOT);
  #pragma unroll
  for (int i = 0; i < RSLOT / 4; ++i) {
    const float4 v = rp[i];
    t += v.x + v.y + v.z + v.w;
  }
  float nll = -pos_ws[r] + 2.0f + __logf(t);
  #pragma unroll
  for (int m = 1; m < 64; m <<= 1) nll += __shfl_xor(nll, m);
  __shared__ float red[4];
  const int lane = threadIdx.x & 63;
  const int wave = threadIdx.x >> 6;
  if (lane == 0) red[wave] = nll;
  __syncthreads();
  if (threadIdx.x == 0) partial[blockIdx.x] = red[0] + red[1] + red[2] + red[3];
}

// ---------------- Kernel 3b: final mean ----------------
__global__ __launch_bounds__(64) void final_kernel(const float* __restrict__ partial,
                                                   float* __restrict__ out) {
  const int lane = threadIdx.x;
  float v = (lane < 32) ? partial[lane] : 0.0f;
  #pragma unroll
  for (int m = 1; m < 64; m <<= 1) v += __shfl_xor(v, m);
  if (lane == 0) out[0] = v * (1.0f / (float)N2);
}

extern "C" void kernel_launch(void* const* d_in, const int* in_sizes, int n_in,
                              void* d_out, int out_size, void* d_ws, size_t ws_size,
                              hipStream_t stream) {
  const float* z1 = (const float*)d_in[0];
  const float* z2 = (const float*)d_in[1];
  float* out = (float*)d_out;

  char* ws = (char*)d_ws;
  unsigned char* zn8 = (unsigned char*)ws;                  // 8192*256 = 2 MB
  float* tsum = (float*)(ws + (size_t)N2 * D);              // 8192*64*4 = 2 MB
  float* rsum = tsum + (size_t)N2 * TSLOT;                  // 8192*36*4 = 1.125 MB
  float* pos_ws = rsum + (size_t)N2 * RSLOT;                // 8192*4 = 32 KB
  float* partial = pos_ws + N2;                             // 32 floats

  // zero tsum+rsum: 8192*100 floats = 204800 float4 = 800 blocks x 256
  hipLaunchKernelGGL(zero_kernel, dim3(800), dim3(256), 0, stream, (float4*)tsum);
  hipLaunchKernelGGL(norm_kernel, dim3(N2 / 4), dim3(256), 0, stream, z1, z2, zn8);
  hipLaunchKernelGGL(simtri_kernel, dim3(NBLK), dim3(256), 0, stream,
                     zn8, tsum, rsum, pos_ws);
  hipLaunchKernelGGL(nll_kernel, dim3(N2 / 256), dim3(256), 0, stream,
                     tsum, rsum, pos_ws, partial);
  hipLaunchKernelGGL(final_kernel, dim3(1), dim3(64), 0, stream, partial, out);
}